// Round 6
// baseline (396.725 us; speedup 1.0000x reference)
//
#include <hip/hip_runtime.h>
#include <cstdint>
#include <cstddef>

#define H      640
#define RH     256
#define NE     5
#define NA     40          // NE * rank
#define NTOK   32768
#define SCAL   2.0f        // alpha/rank = 16/8
#define BK     16
#define BM     32          // tokens/block -> grid 1024, 4 blocks/CU resident
#define NT     (H / BK)    // 40 K-tiles

__device__ __forceinline__ float4 ld4(const float* p) {
    return *reinterpret_cast<const float4*>(p);
}

// async global->LDS, 16B/lane: dest = wave-uniform base, lane offset implicit
__device__ __forceinline__ void gload16(const float* g, float* lds_base) {
    __builtin_amdgcn_global_load_lds(
        (const __attribute__((address_space(1))) void*)g,
        (__attribute__((address_space(3))) void*)lds_base, 16, 0, 0);
}

// ---------------------------------------------------------------------------
// Kernel 1: router (x@W1 -> silu -> @W2 -> softmax -> top2) + low = x@A.
// Round-3 structure (BM=32, 256 thr, 2-token x 16+4-col thread tile, ~64-90
// VGPR) with:
//  - 28.3 KB LDS (single ws buffer, unpadded as_, epilogue arrays aliased
//    onto the loop pool) -> 5 blocks/CU capacity, grid 1024 all-resident.
//  - W1 tile staged via global_load_lds dwordx4 (async, no VGPR round-trip).
//  - x/A loads issued BEFORE compute (land under 1280 FMAs), ds_write after
//    the barrier. W1 gload latency between the two barriers is covered by
//    cross-block waves (4 blocks/CU, not barrier-synced with each other).
// ---------------------------------------------------------------------------
__global__ __launch_bounds__(256)
void k_router(const float* __restrict__ x, const float* __restrict__ W1,
              const float* __restrict__ b1v, const float* __restrict__ W2,
              const float* __restrict__ b2v, const float* __restrict__ A,
              float* __restrict__ route_c, int* __restrict__ route_idx)
{
    __shared__ float ws[BK][RH];               // 16 KB, gload_lds dest (linear)
    __shared__ float w2s[RH * NE];             // 5 KB
    __shared__ float b1s[RH];                  // 1 KB
    __shared__ __align__(16) char pool[6400];  // loop: xs+as_ | epi: low+logit
    float (*xs)[20]       = reinterpret_cast<float (*)[20]>(pool);         // [32][20]
    float (*as_)[NA]      = reinterpret_cast<float (*)[NA]>(pool + 2560);  // [16][40]
    float (*low_lds)[NA]  = reinterpret_cast<float (*)[NA]>(pool);         // [32][40]
    float (*logit_lds)[8] = reinterpret_cast<float (*)[8]>(pool + 5120);   // [32][8]

    const int tid  = threadIdx.x;
    const int row0 = blockIdx.x * BM;
    const int tm   = tid >> 4;
    const int tn   = tid & 15;
    const int lane = tid & 63;
    const int wv   = tid >> 6;

    // staging maps (hoisted)
    const int xrow = tid >> 2, xc = tid & 3;     // x tile: 128 f4 (tid<128)
    const int arow = tid / 10, ac4 = tid % 10;   // A tile: 160 f4 (tid<160)
    const int ae = ac4 >> 1, ar0 = (ac4 & 1) * 4;
    const float* xsrc = x + (size_t)(row0 + xrow) * H + xc * 4;
    const float* asrc = A + ((size_t)ae * H + arow) * 8 + ar0;

    for (int i = tid; i < RH * NE; i += 256) w2s[i] = W2[i];
    if (tid < RH) b1s[tid] = b1v[tid];

    // ---- prologue: stage tile 0 ----
    #pragma unroll
    for (int i = 0; i < 4; i++)
        gload16(W1 + (size_t)(wv * 4 + i) * RH + lane * 4, &ws[wv * 4 + i][0]);
    if (tid < 128) {
        float4 xr = ld4(xsrc);
        *reinterpret_cast<float4*>(&xs[xrow][xc * 4]) = xr;
    }
    if (tid < 160) {
        float4 ar = ld4(asrc);
        *reinterpret_cast<float4*>(&as_[arow][ac4 * 4]) = ar;
    }
    __syncthreads();

    float acc[2][16];
    #pragma unroll
    for (int j = 0; j < 2; j++)
        #pragma unroll
        for (int c = 0; c < 16; c++) acc[j][c] = 0.f;
    float accl[2][4];
    #pragma unroll
    for (int j = 0; j < 2; j++)
        #pragma unroll
        for (int c = 0; c < 4; c++) accl[j][c] = 0.f;

    for (int t = 0; t < NT; ++t) {
        const bool more = (t + 1 < NT);
        const int k0n = (t + 1) * BK;
        float4 xr, ar;
        if (more) {                         // issue early; lands under compute
            if (tid < 128) xr = ld4(xsrc + k0n);
            if (tid < 160) ar = ld4(asrc + (size_t)k0n * 8);
        }

        // ---- compute tile t ----
        #pragma unroll
        for (int kk4 = 0; kk4 < BK; kk4 += 4) {
            float4 xa0 = *reinterpret_cast<const float4*>(&xs[2 * tm + 0][kk4]);
            float4 xa1 = *reinterpret_cast<const float4*>(&xs[2 * tm + 1][kk4]);
            #pragma unroll
            for (int u = 0; u < 4; u++) {
                float bb[16];
                #pragma unroll
                for (int q = 0; q < 4; q++)
                    *reinterpret_cast<float4*>(&bb[q * 4]) =
                        *reinterpret_cast<const float4*>(&ws[kk4 + u][(tn + 16 * q) * 4]);
                float lb[4];
                *reinterpret_cast<float4*>(lb) =
                    *reinterpret_cast<const float4*>(&as_[kk4 + u][tn * 4]);
                float av0 = (u == 0) ? xa0.x : (u == 1) ? xa0.y : (u == 2) ? xa0.z : xa0.w;
                float av1 = (u == 0) ? xa1.x : (u == 1) ? xa1.y : (u == 2) ? xa1.z : xa1.w;
                #pragma unroll
                for (int c = 0; c < 16; c++) {
                    acc[0][c] = fmaf(av0, bb[c], acc[0][c]);
                    acc[1][c] = fmaf(av1, bb[c], acc[1][c]);
                }
                #pragma unroll
                for (int c = 0; c < 4; c++) {
                    accl[0][c] = fmaf(av0, lb[c], accl[0][c]);
                    accl[1][c] = fmaf(av1, lb[c], accl[1][c]);
                }
            }
        }

        __syncthreads();                    // all waves done reading tile t
        if (more) {
            #pragma unroll
            for (int i = 0; i < 4; i++)
                gload16(W1 + ((size_t)k0n + wv * 4 + i) * RH + lane * 4,
                        &ws[wv * 4 + i][0]);
            if (tid < 128)
                *reinterpret_cast<float4*>(&xs[xrow][xc * 4]) = xr;
            if (tid < 160)
                *reinterpret_cast<float4*>(&as_[arow][ac4 * 4]) = ar;
        }
        __syncthreads();                    // drains vmcnt (gload) + lgkm
    }

    // ---- epilogue (pool aliased to low_lds / logit_lds) ----
    if (tn < 10) {
        #pragma unroll
        for (int j = 0; j < 2; j++)
            *reinterpret_cast<float4*>(&low_lds[2 * tm + j][tn * 4]) =
                *reinterpret_cast<float4*>(&accl[j][0]);
    }

    float part[2][5];
    #pragma unroll
    for (int j = 0; j < 2; j++)
        #pragma unroll
        for (int e = 0; e < 5; e++) part[j][e] = 0.f;

    #pragma unroll
    for (int q = 0; q < 4; q++)
        #pragma unroll
        for (int i4 = 0; i4 < 4; i4++) {
            int col = (tn + 16 * q) * 4 + i4;
            float bbias = b1s[col];
            float w2r[5];
            #pragma unroll
            for (int e = 0; e < 5; e++) w2r[e] = w2s[col * 5 + e];
            #pragma unroll
            for (int j = 0; j < 2; j++) {
                float v = acc[j][q * 4 + i4] + bbias;
                float s = __fdividef(v, 1.f + __expf(-v));   // silu
                #pragma unroll
                for (int e = 0; e < 5; e++) part[j][e] = fmaf(s, w2r[e], part[j][e]);
            }
        }

    #pragma unroll
    for (int j = 0; j < 2; j++)
        #pragma unroll
        for (int e = 0; e < 5; e++) {
            float v = part[j][e];
            v += __shfl_xor(v, 1);
            v += __shfl_xor(v, 2);
            v += __shfl_xor(v, 4);
            v += __shfl_xor(v, 8);
            part[j][e] = v;
        }

    if (tn == 0) {
        #pragma unroll
        for (int j = 0; j < 2; j++)
            #pragma unroll
            for (int e = 0; e < 5; e++) logit_lds[2 * tm + j][e] = part[j][e];
    }
    __syncthreads();

    if (tid < BM) {
        const int tk = tid;
        float l0 = logit_lds[tk][0] + b2v[0];
        float l1 = logit_lds[tk][1] + b2v[1];
        float l2 = logit_lds[tk][2] + b2v[2];
        float l3 = logit_lds[tk][3] + b2v[3];
        float l4 = logit_lds[tk][4] + b2v[4];
        int   i0 = 0;  float m0 = l0;
        int   i1 = -1; float m1 = -3.4e38f;
        if (l1 > m0) { m1 = m0; i1 = i0; m0 = l1; i0 = 1; } else if (l1 > m1) { m1 = l1; i1 = 1; }
        if (l2 > m0) { m1 = m0; i1 = i0; m0 = l2; i0 = 2; } else if (l2 > m1) { m1 = l2; i1 = 2; }
        if (l3 > m0) { m1 = m0; i1 = i0; m0 = l3; i0 = 3; } else if (l3 > m1) { m1 = l3; i1 = 3; }
        if (l4 > m0) { m1 = m0; i1 = i0; m0 = l4; i0 = 4; } else if (l4 > m1) { m1 = l4; i1 = 4; }
        float w1r = __expf(m1 - m0);
        float inv = __fdividef(1.f, 1.f + w1r);
        float c0 = inv * SCAL;
        float c1 = w1r * inv * SCAL;
        int gt = row0 + tk;
        #pragma unroll
        for (int r4 = 0; r4 < 2; r4++) {
            float4 v0 = ld4(&low_lds[tk][i0 * 8 + r4 * 4]);
            v0.x *= c0; v0.y *= c0; v0.z *= c0; v0.w *= c0;
            *reinterpret_cast<float4*>(&route_c[(size_t)gt * 16 + r4 * 4]) = v0;
            float4 v1 = ld4(&low_lds[tk][i1 * 8 + r4 * 4]);
            v1.x *= c1; v1.y *= c1; v1.z *= c1; v1.w *= c1;
            *reinterpret_cast<float4*>(&route_c[(size_t)gt * 16 + 8 + r4 * 4]) = v1;
        }
        route_idx[gt * 2 + 0] = i0;
        route_idx[gt * 2 + 1] = i1;
    }
}

// ---------------------------------------------------------------------------
// Kernel 2: out[t] = base[t] + sum_j c[t][j] * Bm_row[idx_j][:]
// All of Bm (40x640 f32 = 102.4 KB) staged in LDS. 512 thr (8 waves), one
// wave per token at a time; grid = 256 blocks * 128 tokens.
// ---------------------------------------------------------------------------
__global__ __launch_bounds__(512)
void k_combine(const float* __restrict__ base, const float* __restrict__ Bm,
               const float* __restrict__ route_c, const int* __restrict__ route_idx,
               float* __restrict__ out)
{
    __shared__ float bs[NA][H];
    const int tid = threadIdx.x;
    for (int i4 = tid; i4 < NA * H / 4; i4 += 512)
        reinterpret_cast<float4*>(&bs[0][0])[i4] = reinterpret_cast<const float4*>(Bm)[i4];
    __syncthreads();

    const int w    = tid >> 6;
    const int lane = tid & 63;

    for (int it = 0; it < 16; it++) {
        int t = blockIdx.x * 128 + w * 16 + it;
        t = __builtin_amdgcn_readfirstlane(t);
        const int e0 = route_idx[t * 2 + 0];
        const int e1 = route_idx[t * 2 + 1];
        float cc[16];
        #pragma unroll
        for (int q = 0; q < 4; q++)
            *reinterpret_cast<float4*>(&cc[q * 4]) = ld4(route_c + (size_t)t * 16 + q * 4);

        const float* brow0 = &bs[e0 * 8][0];
        const float* brow1 = &bs[e1 * 8][0];
        const float* bp = base + (size_t)t * H;
        float*       op = out  + (size_t)t * H;

        #pragma unroll
        for (int i = 0; i < 2; i++) {
            int h = i * 256 + lane * 4;
            float4 a = ld4(bp + h);
            #pragma unroll
            for (int j = 0; j < 8; j++) {
                float4 bv = *reinterpret_cast<const float4*>(brow0 + j * H + h);
                a.x = fmaf(cc[j], bv.x, a.x); a.y = fmaf(cc[j], bv.y, a.y);
                a.z = fmaf(cc[j], bv.z, a.z); a.w = fmaf(cc[j], bv.w, a.w);
            }
            #pragma unroll
            for (int j = 0; j < 8; j++) {
                float4 bv = *reinterpret_cast<const float4*>(brow1 + j * H + h);
                a.x = fmaf(cc[8 + j], bv.x, a.x); a.y = fmaf(cc[8 + j], bv.y, a.y);
                a.z = fmaf(cc[8 + j], bv.z, a.z); a.w = fmaf(cc[8 + j], bv.w, a.w);
            }
            *reinterpret_cast<float4*>(op + h) = a;
        }
        {
            int h = 512 + lane * 2;
            float2 a = *reinterpret_cast<const float2*>(bp + h);
            #pragma unroll
            for (int j = 0; j < 8; j++) {
                float2 bv = *reinterpret_cast<const float2*>(brow0 + j * H + h);
                a.x = fmaf(cc[j], bv.x, a.x); a.y = fmaf(cc[j], bv.y, a.y);
            }
            #pragma unroll
            for (int j = 0; j < 8; j++) {
                float2 bv = *reinterpret_cast<const float2*>(brow1 + j * H + h);
                a.x = fmaf(cc[8 + j], bv.x, a.x); a.y = fmaf(cc[8 + j], bv.y, a.y);
            }
            *reinterpret_cast<float2*>(op + h) = a;
        }
    }
}

extern "C" void kernel_launch(void* const* d_in, const int* in_sizes, int n_in,
                              void* d_out, int out_size, void* d_ws, size_t ws_size,
                              hipStream_t stream)
{
    const float* x  = (const float*)d_in[0];
    const float* bo = (const float*)d_in[1];
    const float* W1 = (const float*)d_in[2];
    const float* b1 = (const float*)d_in[3];
    const float* W2 = (const float*)d_in[4];
    const float* b2 = (const float*)d_in[5];
    const float* A  = (const float*)d_in[6];
    const float* Bm = (const float*)d_in[7];
    float* out = (float*)d_out;

    float* route_c   = (float*)d_ws;                                   // 32768*16 f32 = 2 MB
    int*   route_idx = (int*)((char*)d_ws + (size_t)NTOK * 16 * 4);    // 32768*2 i32 = 256 KB

    k_router<<<dim3(NTOK / BM), dim3(256), 0, stream>>>(
        x, W1, b1, W2, b2, A, route_c, route_idx);
    k_combine<<<dim3(256), dim3(512), 0, stream>>>(
        bo, Bm, route_c, route_idx, out);
}

// Round 7
// 273.570 us; speedup vs baseline: 1.4502x; 1.4502x over previous
//
#include <hip/hip_runtime.h>
#include <cstdint>
#include <cstddef>

#define H      640
#define RH     256
#define NE     5
#define NA     40          // NE * rank
#define NTOK   32768
#define SCAL   2.0f        // alpha/rank = 16/8
#define BK     16
#define BM     32          // tokens/block; grid 1024 -> 4 blocks/CU resident
#define NT     (H / BK)    // 40 K-tiles

__device__ __forceinline__ float4 ld4(const float* p) {
    return *reinterpret_cast<const float4*>(p);
}

// ---------------------------------------------------------------------------
// Kernel 1: router (x@W1 -> silu -> @W2 -> softmax -> top2) + low = x@A.
// R3's proven simple loop (sync; stage; sync; compute) with a 4-token x
// 16-col thread tile (was 2x16): LDS reads per FMA halve (6 b128 / 80 FMA),
// address VALU per FMA halves, W1 stage bytes amortize 2x. 128 threads
// (tm=tid>>4 in [0,8) owning tokens 4tm..4tm+3; tn=tid&15 owning cols
// (tn+16q)*4+i4), BM=32, grid 1024. __launch_bounds__(128,3) caps VGPR at
// ~170: fits acc[4][16]+accl[4][4]=80 + operands without R4's spill, keeps
// 2 waves/SIMD + 4 independently-phased blocks/CU for latency cover.
// ---------------------------------------------------------------------------
__global__ __launch_bounds__(128, 3)
void k_router(const float* __restrict__ x, const float* __restrict__ W1,
              const float* __restrict__ b1v, const float* __restrict__ W2,
              const float* __restrict__ b2v, const float* __restrict__ A,
              float* __restrict__ route_c, int* __restrict__ route_idx)
{
    __shared__ float ws[BK][RH];               // 16 KB
    __shared__ float w2s[RH * NE];             // 5 KB
    __shared__ float b1s[RH];                  // 1 KB
    __shared__ __align__(16) char pool[6400];  // loop: xs+as_ | epi: low+logit
    float (*xs)[20]       = reinterpret_cast<float (*)[20]>(pool);         // [32][20]
    float (*as_)[NA]      = reinterpret_cast<float (*)[NA]>(pool + 2560);  // [16][40]
    float (*low_lds)[NA]  = reinterpret_cast<float (*)[NA]>(pool);         // [32][40]
    float (*logit_lds)[8] = reinterpret_cast<float (*)[8]>(pool + 5120);   // [32][8]

    const int tid  = threadIdx.x;
    const int row0 = blockIdx.x * BM;
    const int tm   = tid >> 4;
    const int tn   = tid & 15;

    // staging maps (hoisted)
    const int xrow = tid >> 2, xc = tid & 3;       // x: 128 f4, 1/thread
    const int wrow = tid >> 6, wc4 = tid & 63;     // W1: 8 f4/thread
    const int arow0 = tid / 10,        ac0 = tid % 10;          // A pass 0
    const int arow1 = (tid + 128)/10,  ac1 = (tid + 128) % 10;  // A pass 1 (tid<32)
    const float* xsrc  = x + (size_t)(row0 + xrow) * H + xc * 4;
    const float* asrc0 = A + ((size_t)(ac0 >> 1) * H + arow0) * 8 + (ac0 & 1) * 4;
    const float* asrc1 = A + ((size_t)(ac1 >> 1) * H + arow1) * 8 + (ac1 & 1) * 4;

    for (int i = tid; i < RH * NE; i += 128) w2s[i] = W2[i];
    for (int i = tid; i < RH; i += 128) b1s[i] = b1v[i];

    float acc[4][16];
    #pragma unroll
    for (int j = 0; j < 4; j++)
        #pragma unroll
        for (int c = 0; c < 16; c++) acc[j][c] = 0.f;
    float accl[4][4];
    #pragma unroll
    for (int j = 0; j < 4; j++)
        #pragma unroll
        for (int c = 0; c < 4; c++) accl[j][c] = 0.f;

    for (int t = 0; t < NT; ++t) {
        const int k0 = t * BK;
        __syncthreads();
        // stage x tile [32][16] (1 f4/thread)
        *reinterpret_cast<float4*>(&xs[xrow][xc * 4]) = ld4(xsrc + k0);
        // stage W1 tile [16][256]: row 2i+wrow, one conflict-free b128/row/wave
        #pragma unroll
        for (int i = 0; i < 8; i++)
            *reinterpret_cast<float4*>(&ws[2 * i + wrow][wc4 * 4]) =
                ld4(W1 + (size_t)(k0 + 2 * i + wrow) * RH + wc4 * 4);
        // stage A tile [16][40]: 160 f4 over 128 threads (2 passes)
        *reinterpret_cast<float4*>(&as_[arow0][ac0 * 4]) = ld4(asrc0 + (size_t)k0 * 8);
        if (tid < 32)
            *reinterpret_cast<float4*>(&as_[arow1][ac1 * 4]) = ld4(asrc1 + (size_t)k0 * 8);
        __syncthreads();

        #pragma unroll
        for (int kk4 = 0; kk4 < BK; kk4 += 4) {
            float4 xa[4];
            #pragma unroll
            for (int j = 0; j < 4; j++)
                xa[j] = *reinterpret_cast<const float4*>(&xs[4 * tm + j][kk4]);
            #pragma unroll
            for (int u = 0; u < 4; u++) {
                float bb[16];
                #pragma unroll
                for (int q = 0; q < 4; q++)
                    *reinterpret_cast<float4*>(&bb[q * 4]) =
                        *reinterpret_cast<const float4*>(&ws[kk4 + u][(tn + 16 * q) * 4]);
                float lb[4];
                *reinterpret_cast<float4*>(lb) =
                    *reinterpret_cast<const float4*>(&as_[kk4 + u][tn * 4]);
                #pragma unroll
                for (int j = 0; j < 4; j++) {
                    float av = (u == 0) ? xa[j].x : (u == 1) ? xa[j].y
                             : (u == 2) ? xa[j].z : xa[j].w;
                    #pragma unroll
                    for (int c = 0; c < 16; c++)
                        acc[j][c] = fmaf(av, bb[c], acc[j][c]);
                    #pragma unroll
                    for (int c = 0; c < 4; c++)
                        accl[j][c] = fmaf(av, lb[c], accl[j][c]);
                }
            }
        }
    }

    __syncthreads();   // all compute done before aliased epilogue writes

    // publish low values (lanes owning real cols)
    if (tn < 10) {
        #pragma unroll
        for (int j = 0; j < 4; j++)
            *reinterpret_cast<float4*>(&low_lds[4 * tm + j][tn * 4]) =
                *reinterpret_cast<float4*>(&accl[j][0]);
    }

    // silu + b1, partial logits over this thread's 16 cols
    float part[4][5];
    #pragma unroll
    for (int j = 0; j < 4; j++)
        #pragma unroll
        for (int e = 0; e < 5; e++) part[j][e] = 0.f;

    #pragma unroll
    for (int q = 0; q < 4; q++)
        #pragma unroll
        for (int i4 = 0; i4 < 4; i4++) {
            int col = (tn + 16 * q) * 4 + i4;
            float bbias = b1s[col];
            float w2r[5];
            #pragma unroll
            for (int e = 0; e < 5; e++) w2r[e] = w2s[col * 5 + e];
            #pragma unroll
            for (int j = 0; j < 4; j++) {
                float v = acc[j][q * 4 + i4] + bbias;
                float s = __fdividef(v, 1.f + __expf(-v));   // silu
                #pragma unroll
                for (int e = 0; e < 5; e++) part[j][e] = fmaf(s, w2r[e], part[j][e]);
            }
        }

    // reduce partial logits across the 16 tn-lanes
    #pragma unroll
    for (int j = 0; j < 4; j++)
        #pragma unroll
        for (int e = 0; e < 5; e++) {
            float v = part[j][e];
            v += __shfl_xor(v, 1);
            v += __shfl_xor(v, 2);
            v += __shfl_xor(v, 4);
            v += __shfl_xor(v, 8);
            part[j][e] = v;
        }

    if (tn == 0) {
        #pragma unroll
        for (int j = 0; j < 4; j++)
            #pragma unroll
            for (int e = 0; e < 5; e++) logit_lds[4 * tm + j][e] = part[j][e];
    }
    __syncthreads();

    // one thread per token: top-2 + route_c write
    if (tid < BM) {
        const int tk = tid;
        float l0 = logit_lds[tk][0] + b2v[0];
        float l1 = logit_lds[tk][1] + b2v[1];
        float l2 = logit_lds[tk][2] + b2v[2];
        float l3 = logit_lds[tk][3] + b2v[3];
        float l4 = logit_lds[tk][4] + b2v[4];
        int   i0 = 0;  float m0 = l0;
        int   i1 = -1; float m1 = -3.4e38f;
        if (l1 > m0) { m1 = m0; i1 = i0; m0 = l1; i0 = 1; } else if (l1 > m1) { m1 = l1; i1 = 1; }
        if (l2 > m0) { m1 = m0; i1 = i0; m0 = l2; i0 = 2; } else if (l2 > m1) { m1 = l2; i1 = 2; }
        if (l3 > m0) { m1 = m0; i1 = i0; m0 = l3; i0 = 3; } else if (l3 > m1) { m1 = l3; i1 = 3; }
        if (l4 > m0) { m1 = m0; i1 = i0; m0 = l4; i0 = 4; } else if (l4 > m1) { m1 = l4; i1 = 4; }
        float w1r = __expf(m1 - m0);
        float inv = __fdividef(1.f, 1.f + w1r);
        float c0 = inv * SCAL;
        float c1 = w1r * inv * SCAL;
        int gt = row0 + tk;
        #pragma unroll
        for (int r4 = 0; r4 < 2; r4++) {
            float4 v0 = ld4(&low_lds[tk][i0 * 8 + r4 * 4]);
            v0.x *= c0; v0.y *= c0; v0.z *= c0; v0.w *= c0;
            *reinterpret_cast<float4*>(&route_c[(size_t)gt * 16 + r4 * 4]) = v0;
            float4 v1 = ld4(&low_lds[tk][i1 * 8 + r4 * 4]);
            v1.x *= c1; v1.y *= c1; v1.z *= c1; v1.w *= c1;
            *reinterpret_cast<float4*>(&route_c[(size_t)gt * 16 + 8 + r4 * 4]) = v1;
        }
        route_idx[gt * 2 + 0] = i0;
        route_idx[gt * 2 + 1] = i1;
    }
}

// ---------------------------------------------------------------------------
// Kernel 2: out[t] = base[t] + sum_j c[t][j] * Bm_row[idx_j][:]
// All of Bm (40x640 f32 = 102.4 KB) staged in LDS. 512 thr (8 waves), one
// wave per token at a time; grid = 256 blocks * 128 tokens. ~20 us, near the
// 170 MB HBM floor for base+out traffic.
// ---------------------------------------------------------------------------
__global__ __launch_bounds__(512)
void k_combine(const float* __restrict__ base, const float* __restrict__ Bm,
               const float* __restrict__ route_c, const int* __restrict__ route_idx,
               float* __restrict__ out)
{
    __shared__ float bs[NA][H];
    const int tid = threadIdx.x;
    for (int i4 = tid; i4 < NA * H / 4; i4 += 512)
        reinterpret_cast<float4*>(&bs[0][0])[i4] = reinterpret_cast<const float4*>(Bm)[i4];
    __syncthreads();

    const int w    = tid >> 6;
    const int lane = tid & 63;

    for (int it = 0; it < 16; it++) {
        int t = blockIdx.x * 128 + w * 16 + it;
        t = __builtin_amdgcn_readfirstlane(t);
        const int e0 = route_idx[t * 2 + 0];
        const int e1 = route_idx[t * 2 + 1];
        float cc[16];
        #pragma unroll
        for (int q = 0; q < 4; q++)
            *reinterpret_cast<float4*>(&cc[q * 4]) = ld4(route_c + (size_t)t * 16 + q * 4);

        const float* brow0 = &bs[e0 * 8][0];
        const float* brow1 = &bs[e1 * 8][0];
        const float* bp = base + (size_t)t * H;
        float*       op = out  + (size_t)t * H;

        #pragma unroll
        for (int i = 0; i < 2; i++) {
            int h = i * 256 + lane * 4;
            float4 a = ld4(bp + h);
            #pragma unroll
            for (int j = 0; j < 8; j++) {
                float4 bv = *reinterpret_cast<const float4*>(brow0 + j * H + h);
                a.x = fmaf(cc[j], bv.x, a.x); a.y = fmaf(cc[j], bv.y, a.y);
                a.z = fmaf(cc[j], bv.z, a.z); a.w = fmaf(cc[j], bv.w, a.w);
            }
            #pragma unroll
            for (int j = 0; j < 8; j++) {
                float4 bv = *reinterpret_cast<const float4*>(brow1 + j * H + h);
                a.x = fmaf(cc[8 + j], bv.x, a.x); a.y = fmaf(cc[8 + j], bv.y, a.y);
                a.z = fmaf(cc[8 + j], bv.z, a.z); a.w = fmaf(cc[8 + j], bv.w, a.w);
            }
            *reinterpret_cast<float4*>(op + h) = a;
        }
        {
            int h = 512 + lane * 2;
            float2 a = *reinterpret_cast<const float2*>(bp + h);
            #pragma unroll
            for (int j = 0; j < 8; j++) {
                float2 bv = *reinterpret_cast<const float2*>(brow0 + j * H + h);
                a.x = fmaf(cc[j], bv.x, a.x); a.y = fmaf(cc[j], bv.y, a.y);
            }
            #pragma unroll
            for (int j = 0; j < 8; j++) {
                float2 bv = *reinterpret_cast<const float2*>(brow1 + j * H + h);
                a.x = fmaf(cc[8 + j], bv.x, a.x); a.y = fmaf(cc[8 + j], bv.y, a.y);
            }
            *reinterpret_cast<float2*>(op + h) = a;
        }
    }
}

extern "C" void kernel_launch(void* const* d_in, const int* in_sizes, int n_in,
                              void* d_out, int out_size, void* d_ws, size_t ws_size,
                              hipStream_t stream)
{
    const float* x  = (const float*)d_in[0];
    const float* bo = (const float*)d_in[1];
    const float* W1 = (const float*)d_in[2];
    const float* b1 = (const float*)d_in[3];
    const float* W2 = (const float*)d_in[4];
    const float* b2 = (const float*)d_in[5];
    const float* A  = (const float*)d_in[6];
    const float* Bm = (const float*)d_in[7];
    float* out = (float*)d_out;

    float* route_c   = (float*)d_ws;                                   // 32768*16 f32 = 2 MB
    int*   route_idx = (int*)((char*)d_ws + (size_t)NTOK * 16 * 4);    // 32768*2 i32 = 256 KB

    k_router<<<dim3(NTOK / BM), dim3(128), 0, stream>>>(
        x, W1, b1, W2, b2, A, route_c, route_idx);
    k_combine<<<dim3(256), dim3(512), 0, stream>>>(
        bo, Bm, route_c, route_idx, out);
}

// Round 8
// 265.671 us; speedup vs baseline: 1.4933x; 1.0297x over previous
//
#include <hip/hip_runtime.h>
#include <cstdint>
#include <cstddef>

#define H      640
#define RH     256
#define NE     5
#define NA     40          // NE * rank
#define NTOK   32768
#define SCAL   2.0f        // alpha/rank = 16/8
#define BK     16
#define BM     32          // tokens/block; grid 1024 -> 4 blocks/CU resident
#define NT     (H / BK)    // 40 K-tiles

__device__ __forceinline__ float4 ld4(const float* p) {
    return *reinterpret_cast<const float4*>(p);
}

// ---------------------------------------------------------------------------
// Kernel 1: router (x@W1 -> silu -> @W2 -> softmax -> top2) + low = x@A.
// R3's proven simple loop (sync; stage; sync; compute), 256 thr, BM=32,
// grid 1024 = 4 blocks/CU = 16 waves/CU (the TLP that R3 proved necessary),
// but with an 8x32 thread map: tm=tid>>5 owns 4 tokens, tn=tid&31 owns 8
// cols ((tn+32q)*4+i4, q<2). Gains vs R3's 2x16 tile at equal TLP:
//  - xa reads are wave-uniform (32 lanes share tm) -> LDS broadcast, free
//  - bb reads: 2 per u (was 4), 512B contiguous per wave, conflict-free
//  - ds_read instrs/FMA 0.1375 -> 0.11, addressing VALU halves per FMA
// acc is 48 regs -> __launch_bounds__(256,4) caps VGPR at 128 safely.
// ---------------------------------------------------------------------------
__global__ __launch_bounds__(256, 4)
void k_router(const float* __restrict__ x, const float* __restrict__ W1,
              const float* __restrict__ b1v, const float* __restrict__ W2,
              const float* __restrict__ b2v, const float* __restrict__ A,
              float* __restrict__ route_c, int* __restrict__ route_idx)
{
    __shared__ float ws[BK][RH];               // 16 KB
    __shared__ float w2s[RH * NE];             // 5 KB
    __shared__ float b1s[RH];                  // 1 KB
    __shared__ __align__(16) char pool[6400];  // loop: xs+as_ | epi: low+logit
    float (*xs)[20]       = reinterpret_cast<float (*)[20]>(pool);         // [32][20]
    float (*as_)[NA]      = reinterpret_cast<float (*)[NA]>(pool + 2560);  // [16][40]
    float (*low_lds)[NA]  = reinterpret_cast<float (*)[NA]>(pool);         // [32][40]
    float (*logit_lds)[8] = reinterpret_cast<float (*)[8]>(pool + 5120);   // [32][8]

    const int tid  = threadIdx.x;
    const int row0 = blockIdx.x * BM;
    const int tm   = tid >> 5;          // 0..7, owns tokens 4tm..4tm+3
    const int tn   = tid & 31;          // 0..31, owns cols (tn+32q)*4+i4

    // staging maps (hoisted)
    const int xrow = tid >> 2, xc = tid & 3;       // x: 128 f4 (tid<128)
    const int arow = tid / 10, ac4 = tid % 10;     // A: 160 f4 (tid<160)
    const int ae = ac4 >> 1, ar0 = (ac4 & 1) * 4;
    const float* xsrc = x + (size_t)(row0 + xrow) * H + xc * 4;
    const float* asrc = A + ((size_t)ae * H + arow) * 8 + ar0;

    for (int i = tid; i < RH * NE; i += 256) w2s[i] = W2[i];
    if (tid < RH) b1s[tid] = b1v[tid];

    float acc[4][8];
    #pragma unroll
    for (int j = 0; j < 4; j++)
        #pragma unroll
        for (int c = 0; c < 8; c++) acc[j][c] = 0.f;
    float accl[4][4];
    #pragma unroll
    for (int j = 0; j < 4; j++)
        #pragma unroll
        for (int c = 0; c < 4; c++) accl[j][c] = 0.f;

    for (int t = 0; t < NT; ++t) {
        const int k0 = t * BK;
        __syncthreads();
        // stage x tile [32][16] (1 f4, tid<128)
        if (tid < 128)
            *reinterpret_cast<float4*>(&xs[xrow][xc * 4]) = ld4(xsrc + k0);
        // stage W1 tile [16][256] (4 f4/thread, linear, conflict-free)
        #pragma unroll
        for (int i = 0; i < 4; i++) {
            int idx4 = tid + i * 256;
            int row = idx4 >> 6, c4 = idx4 & 63;
            *reinterpret_cast<float4*>(&ws[row][c4 * 4]) =
                ld4(W1 + (size_t)(k0 + row) * RH + c4 * 4);
        }
        // stage A tile [16][40] (tid<160)
        if (tid < 160)
            *reinterpret_cast<float4*>(&as_[arow][ac4 * 4]) =
                ld4(asrc + (size_t)k0 * 8);
        __syncthreads();

        #pragma unroll
        for (int kk4 = 0; kk4 < BK; kk4 += 4) {
            float4 xa[4];
            #pragma unroll
            for (int j = 0; j < 4; j++)   // wave-uniform addr -> broadcast
                xa[j] = *reinterpret_cast<const float4*>(&xs[4 * tm + j][kk4]);
            #pragma unroll
            for (int u = 0; u < 4; u++) {
                float bb[8];
                #pragma unroll
                for (int q = 0; q < 2; q++)
                    *reinterpret_cast<float4*>(&bb[q * 4]) =
                        *reinterpret_cast<const float4*>(&ws[kk4 + u][(tn + 32 * q) * 4]);
                float lb[4];
                *reinterpret_cast<float4*>(lb) =
                    *reinterpret_cast<const float4*>(&as_[kk4 + u][tn * 4]);
                #pragma unroll
                for (int j = 0; j < 4; j++) {
                    float av = (u == 0) ? xa[j].x : (u == 1) ? xa[j].y
                             : (u == 2) ? xa[j].z : xa[j].w;
                    #pragma unroll
                    for (int c = 0; c < 8; c++)
                        acc[j][c] = fmaf(av, bb[c], acc[j][c]);
                    #pragma unroll
                    for (int c = 0; c < 4; c++)
                        accl[j][c] = fmaf(av, lb[c], accl[j][c]);
                }
            }
        }
    }

    __syncthreads();   // all compute done before aliased epilogue writes

    // publish low values (lanes owning real cols)
    if (tn < 10) {
        #pragma unroll
        for (int j = 0; j < 4; j++)
            *reinterpret_cast<float4*>(&low_lds[4 * tm + j][tn * 4]) =
                *reinterpret_cast<float4*>(&accl[j][0]);
    }

    // silu + b1, partial logits over this thread's 8 cols
    float part[4][5];
    #pragma unroll
    for (int j = 0; j < 4; j++)
        #pragma unroll
        for (int e = 0; e < 5; e++) part[j][e] = 0.f;

    #pragma unroll
    for (int q = 0; q < 2; q++)
        #pragma unroll
        for (int i4 = 0; i4 < 4; i4++) {
            int col = (tn + 32 * q) * 4 + i4;
            float bbias = b1s[col];
            float w2r[5];
            #pragma unroll
            for (int e = 0; e < 5; e++) w2r[e] = w2s[col * 5 + e];
            #pragma unroll
            for (int j = 0; j < 4; j++) {
                float v = acc[j][q * 4 + i4] + bbias;
                float s = __fdividef(v, 1.f + __expf(-v));   // silu
                #pragma unroll
                for (int e = 0; e < 5; e++) part[j][e] = fmaf(s, w2r[e], part[j][e]);
            }
        }

    // reduce partial logits across the 32 tn-lanes (stays within wave half)
    #pragma unroll
    for (int j = 0; j < 4; j++)
        #pragma unroll
        for (int e = 0; e < 5; e++) {
            float v = part[j][e];
            v += __shfl_xor(v, 1);
            v += __shfl_xor(v, 2);
            v += __shfl_xor(v, 4);
            v += __shfl_xor(v, 8);
            v += __shfl_xor(v, 16);
            part[j][e] = v;
        }

    if (tn == 0) {
        #pragma unroll
        for (int j = 0; j < 4; j++)
            #pragma unroll
            for (int e = 0; e < 5; e++) logit_lds[4 * tm + j][e] = part[j][e];
    }
    __syncthreads();

    // one thread per token: top-2 + route_c write
    if (tid < BM) {
        const int tk = tid;
        float l0 = logit_lds[tk][0] + b2v[0];
        float l1 = logit_lds[tk][1] + b2v[1];
        float l2 = logit_lds[tk][2] + b2v[2];
        float l3 = logit_lds[tk][3] + b2v[3];
        float l4 = logit_lds[tk][4] + b2v[4];
        int   i0 = 0;  float m0 = l0;
        int   i1 = -1; float m1 = -3.4e38f;
        if (l1 > m0) { m1 = m0; i1 = i0; m0 = l1; i0 = 1; } else if (l1 > m1) { m1 = l1; i1 = 1; }
        if (l2 > m0) { m1 = m0; i1 = i0; m0 = l2; i0 = 2; } else if (l2 > m1) { m1 = l2; i1 = 2; }
        if (l3 > m0) { m1 = m0; i1 = i0; m0 = l3; i0 = 3; } else if (l3 > m1) { m1 = l3; i1 = 3; }
        if (l4 > m0) { m1 = m0; i1 = i0; m0 = l4; i0 = 4; } else if (l4 > m1) { m1 = l4; i1 = 4; }
        float w1r = __expf(m1 - m0);
        float inv = __fdividef(1.f, 1.f + w1r);
        float c0 = inv * SCAL;
        float c1 = w1r * inv * SCAL;
        int gt = row0 + tk;
        #pragma unroll
        for (int r4 = 0; r4 < 2; r4++) {
            float4 v0 = ld4(&low_lds[tk][i0 * 8 + r4 * 4]);
            v0.x *= c0; v0.y *= c0; v0.z *= c0; v0.w *= c0;
            *reinterpret_cast<float4*>(&route_c[(size_t)gt * 16 + r4 * 4]) = v0;
            float4 v1 = ld4(&low_lds[tk][i1 * 8 + r4 * 4]);
            v1.x *= c1; v1.y *= c1; v1.z *= c1; v1.w *= c1;
            *reinterpret_cast<float4*>(&route_c[(size_t)gt * 16 + 8 + r4 * 4]) = v1;
        }
        route_idx[gt * 2 + 0] = i0;
        route_idx[gt * 2 + 1] = i1;
    }
}

// ---------------------------------------------------------------------------
// Kernel 2: out[t] = base[t] + sum_j c[t][j] * Bm_row[idx_j][:]
// All of Bm (40x640 f32 = 102.4 KB) staged in LDS. 512 thr (8 waves), one
// wave per token at a time; grid = 256 blocks * 128 tokens. ~20 us, near the
// 170 MB HBM floor for base+out traffic.
// ---------------------------------------------------------------------------
__global__ __launch_bounds__(512)
void k_combine(const float* __restrict__ base, const float* __restrict__ Bm,
               const float* __restrict__ route_c, const int* __restrict__ route_idx,
               float* __restrict__ out)
{
    __shared__ float bs[NA][H];
    const int tid = threadIdx.x;
    for (int i4 = tid; i4 < NA * H / 4; i4 += 512)
        reinterpret_cast<float4*>(&bs[0][0])[i4] = reinterpret_cast<const float4*>(Bm)[i4];
    __syncthreads();

    const int w    = tid >> 6;
    const int lane = tid & 63;

    for (int it = 0; it < 16; it++) {
        int t = blockIdx.x * 128 + w * 16 + it;
        t = __builtin_amdgcn_readfirstlane(t);
        const int e0 = route_idx[t * 2 + 0];
        const int e1 = route_idx[t * 2 + 1];
        float cc[16];
        #pragma unroll
        for (int q = 0; q < 4; q++)
            *reinterpret_cast<float4*>(&cc[q * 4]) = ld4(route_c + (size_t)t * 16 + q * 4);

        const float* brow0 = &bs[e0 * 8][0];
        const float* brow1 = &bs[e1 * 8][0];
        const float* bp = base + (size_t)t * H;
        float*       op = out  + (size_t)t * H;

        #pragma unroll
        for (int i = 0; i < 2; i++) {
            int h = i * 256 + lane * 4;
            float4 a = ld4(bp + h);
            #pragma unroll
            for (int j = 0; j < 8; j++) {
                float4 bv = *reinterpret_cast<const float4*>(brow0 + j * H + h);
                a.x = fmaf(cc[j], bv.x, a.x); a.y = fmaf(cc[j], bv.y, a.y);
                a.z = fmaf(cc[j], bv.z, a.z); a.w = fmaf(cc[j], bv.w, a.w);
            }
            #pragma unroll
            for (int j = 0; j < 8; j++) {
                float4 bv = *reinterpret_cast<const float4*>(brow1 + j * H + h);
                a.x = fmaf(cc[8 + j], bv.x, a.x); a.y = fmaf(cc[8 + j], bv.y, a.y);
                a.z = fmaf(cc[8 + j], bv.z, a.z); a.w = fmaf(cc[8 + j], bv.w, a.w);
            }
            *reinterpret_cast<float4*>(op + h) = a;
        }
        {
            int h = 512 + lane * 2;
            float2 a = *reinterpret_cast<const float2*>(bp + h);
            #pragma unroll
            for (int j = 0; j < 8; j++) {
                float2 bv = *reinterpret_cast<const float2*>(brow0 + j * H + h);
                a.x = fmaf(cc[j], bv.x, a.x); a.y = fmaf(cc[j], bv.y, a.y);
            }
            #pragma unroll
            for (int j = 0; j < 8; j++) {
                float2 bv = *reinterpret_cast<const float2*>(brow1 + j * H + h);
                a.x = fmaf(cc[8 + j], bv.x, a.x); a.y = fmaf(cc[8 + j], bv.y, a.y);
            }
            *reinterpret_cast<float2*>(op + h) = a;
        }
    }
}

extern "C" void kernel_launch(void* const* d_in, const int* in_sizes, int n_in,
                              void* d_out, int out_size, void* d_ws, size_t ws_size,
                              hipStream_t stream)
{
    const float* x  = (const float*)d_in[0];
    const float* bo = (const float*)d_in[1];
    const float* W1 = (const float*)d_in[2];
    const float* b1 = (const float*)d_in[3];
    const float* W2 = (const float*)d_in[4];
    const float* b2 = (const float*)d_in[5];
    const float* A  = (const float*)d_in[6];
    const float* Bm = (const float*)d_in[7];
    float* out = (float*)d_out;

    float* route_c   = (float*)d_ws;                                   // 32768*16 f32 = 2 MB
    int*   route_idx = (int*)((char*)d_ws + (size_t)NTOK * 16 * 4);    // 32768*2 i32 = 256 KB

    k_router<<<dim3(NTOK / BM), dim3(256), 0, stream>>>(
        x, W1, b1, W2, b2, A, route_c, route_idx);
    k_combine<<<dim3(256), dim3(512), 0, stream>>>(
        bo, Bm, route_c, route_idx, out);
}